// Round 1
// baseline (135.274 us; speedup 1.0000x reference)
//
#include <hip/hip_runtime.h>
#include <hip/hip_bf16.h>
#include <stdint.h>

// y[p, j] = sum_i Alpha[p, i] * (X_ref[i] . X_in[j])^expK * [Z_ref[i] == Z[j]]
// Fused attention-shaped kernel: QK^T (MFMA bf16) -> square+mask -> PV (MFMA bf16).
// Deterministic i-split with partial buffers + reduce (no atomics).

typedef __attribute__((ext_vector_type(8))) short bf16x8;   // 8 bf16 (4 VGPRs), per guide §3
typedef __attribute__((ext_vector_type(4))) float f32x4;

#define DFEAT  384
#define NREF   8192
#define NIN    8192
#define NPROPS 64
#define BJ 128
#define BI 128
#define BK 32
#define KSTEPS (DFEAT / BK)   // 12

__device__ __forceinline__ void gload_lds16(const void* g, void* l) {
  // async global->LDS, 16B/lane; LDS dest is wave-uniform base + lane*16
  __builtin_amdgcn_global_load_lds(
      (const __attribute__((address_space(1))) void*)g,
      (__attribute__((address_space(3))) void*)l,
      16, 0, 0);
}

__device__ __forceinline__ unsigned short bfbits(float f) {
  __hip_bfloat16 h = __float2bfloat16(f);
  return __builtin_bit_cast(unsigned short, h);
}

__device__ __forceinline__ float pwr(float s, int expK) {
  if (expK == 2) return s * s;          // the only case setup_inputs produces
  float r = 1.0f;
  for (int e = 0; e < expK; ++e) r *= s; // exact for small integer expK
  return r;
}

__global__ void cvt_f32_bf16(const float* __restrict__ in,
                             __hip_bfloat16* __restrict__ out, int n4) {
  int idx = blockIdx.x * blockDim.x + threadIdx.x;
  if (idx >= n4) return;
  float4 v = *reinterpret_cast<const float4*>(in + (size_t)idx * 4);
  ushort4 o;
  o.x = bfbits(v.x); o.y = bfbits(v.y); o.z = bfbits(v.z); o.w = bfbits(v.w);
  *reinterpret_cast<ushort4*>(out + (size_t)idx * 4) = o;
}

__global__ void reduce_partials(const float* __restrict__ partial,
                                float* __restrict__ out, int nsplit) {
  int idx = blockIdx.x * blockDim.x + threadIdx.x;   // over NPROPS*NIN/4
  float4 s = make_float4(0.f, 0.f, 0.f, 0.f);
  for (int sp = 0; sp < nsplit; ++sp) {
    float4 v = *reinterpret_cast<const float4*>(
        partial + (size_t)sp * NPROPS * NIN + (size_t)idx * 4);
    s.x += v.x; s.y += v.y; s.z += v.z; s.w += v.w;
  }
  *reinterpret_cast<float4*>(out + (size_t)idx * 4) = s;
}

__global__ __launch_bounds__(256, 2) void fused_poly_kernel(
    const __hip_bfloat16* __restrict__ Xr,   // [NREF][DFEAT] bf16
    const __hip_bfloat16* __restrict__ Xi,   // [NIN][DFEAT] bf16
    const __hip_bfloat16* __restrict__ Ab,   // [NPROPS][NREF] bf16
    const int* __restrict__ Zrq,             // [NREF]
    const int* __restrict__ Zcq,             // [NIN]
    const int* __restrict__ expKp,
    float* __restrict__ partial,             // [nsplit][NPROPS][NIN]
    int i_per_split)
{
  const int jblk  = blockIdx.x;
  const int split = blockIdx.y;
  const int j0 = jblk * BJ;
  const int i_begin = split * i_per_split;

  const int tid  = threadIdx.x;
  const int wid  = tid >> 6;      // 4 waves
  const int lane = tid & 63;
  const int l15  = lane & 15;
  const int l4   = lane >> 4;     // 0..3
  const int wi   = wid >> 1;      // wave row over i (2)
  const int wj   = wid & 1;       // wave col over j (2)

  __shared__ alignas(16) __hip_bfloat16 lA[BI * BK];    // X_ref tile [128][32]
  __shared__ alignas(16) __hip_bfloat16 lB[BJ * BK];    // X_in  tile [128][32]
  __shared__ alignas(16) __hip_bfloat16 lPT[BJ * BI];   // P^T [j][i], XOR-swizzled
  __shared__ int lZr[BI];
  __shared__ int lZc[BJ];

  const int expK = *expKp;

  if (tid < BJ) lZc[tid] = Zcq[j0 + tid];

  f32x4 accO[4][2];   // O[p=64][j=32 per wave]: 4 p-tiles x 2 j-tiles
  #pragma unroll
  for (int a = 0; a < 4; ++a)
    #pragma unroll
    for (int n = 0; n < 2; ++n)
      accO[a][n] = (f32x4){0.f, 0.f, 0.f, 0.f};

  const int ntiles = i_per_split / BI;
  for (int t = 0; t < ntiles; ++t) {
    const int i0 = i_begin + t * BI;
    if (tid < BI) lZr[tid] = Zrq[i0 + tid];

    f32x4 acc[4][4];   // S subtile 64x64 per wave
    #pragma unroll
    for (int m = 0; m < 4; ++m)
      #pragma unroll
      for (int n = 0; n < 4; ++n)
        acc[m][n] = (f32x4){0.f, 0.f, 0.f, 0.f};

    // ---- QK^T over K=384 ----
    for (int kk = 0; kk < KSTEPS; ++kk) {
      __syncthreads();   // prev reads of lA/lB done (also covers lZr/lZc staging)
      #pragma unroll
      for (int q = 0; q < 2; ++q) {
        const int row  = q * 64 + wid * 16;      // wave-uniform LDS row base
        const int grow = row + (lane >> 2);      // per-lane global row
        const int gcol = kk * BK + (lane & 3) * 8;
        gload_lds16(Xr + (size_t)(i0 + grow) * DFEAT + gcol, &lA[row * BK]);
        gload_lds16(Xi + (size_t)(j0 + grow) * DFEAT + gcol, &lB[row * BK]);
      }
      __syncthreads();   // barrier drains vmcnt -> tiles visible

      bf16x8 aF[4], bF[4];
      #pragma unroll
      for (int m = 0; m < 4; ++m)
        aF[m] = *reinterpret_cast<const bf16x8*>(
            &lA[(wi * 64 + m * 16 + l15) * BK + l4 * 8]);
      #pragma unroll
      for (int n = 0; n < 4; ++n)
        bF[n] = *reinterpret_cast<const bf16x8*>(
            &lB[(wj * 64 + n * 16 + l15) * BK + l4 * 8]);
      #pragma unroll
      for (int m = 0; m < 4; ++m)
        #pragma unroll
        for (int n = 0; n < 4; ++n)
          acc[m][n] = __builtin_amdgcn_mfma_f32_16x16x32_bf16(
              aF[m], bF[n], acc[m][n], 0, 0, 0);
    }

    // ---- mask + pow, write P^T[j][i] to LDS (XOR swizzle on byte offset) ----
    // D layout (verified): row_i = 16*m + 4*l4 + r, col_j = 16*n + l15
    char* pb = (char*)lPT;
    #pragma unroll
    for (int m = 0; m < 4; ++m) {
      const int ir0 = wi * 64 + m * 16 + l4 * 4;
      const int z0 = lZr[ir0 + 0];
      const int z1 = lZr[ir0 + 1];
      const int z2 = lZr[ir0 + 2];
      const int z3 = lZr[ir0 + 3];
      #pragma unroll
      for (int n = 0; n < 4; ++n) {
        const int jl = wj * 64 + n * 16 + l15;
        const int zc = lZc[jl];
        const float p0 = (z0 == zc) ? pwr(acc[m][n][0], expK) : 0.f;
        const float p1 = (z1 == zc) ? pwr(acc[m][n][1], expK) : 0.f;
        const float p2 = (z2 == zc) ? pwr(acc[m][n][2], expK) : 0.f;
        const float p3 = (z3 == zc) ? pwr(acc[m][n][3], expK) : 0.f;
        uint2 v;
        v.x = (uint32_t)bfbits(p0) | ((uint32_t)bfbits(p1) << 16);
        v.y = (uint32_t)bfbits(p2) | ((uint32_t)bfbits(p3) << 16);
        const int off = (jl * (BI * 2) + ir0 * 2) ^ ((jl & 7) << 4);
        *reinterpret_cast<uint2*>(pb + off) = v;
      }
    }
    __syncthreads();   // P^T complete before PV reads

    // ---- PV: O[p][j] += Alpha[p, i-tile] * P ----
    // A = Alpha rows (contig in i); B = P^T rows (contig in i, swizzled)
    #pragma unroll
    for (int ks = 0; ks < 4; ++ks) {
      bf16x8 aP[4];
      #pragma unroll
      for (int a = 0; a < 4; ++a)
        aP[a] = *reinterpret_cast<const bf16x8*>(
            Ab + (size_t)(a * 16 + l15) * NREF + i0 + ks * 32 + l4 * 8);
      #pragma unroll
      for (int n = 0; n < 2; ++n) {
        const int jl = wid * 32 + n * 16 + l15;
        const int off = (jl * (BI * 2) + (ks * 32 + l4 * 8) * 2) ^ ((jl & 7) << 4);
        const bf16x8 bP = *reinterpret_cast<const bf16x8*>(pb + off);
        #pragma unroll
        for (int a = 0; a < 4; ++a)
          accO[a][n] = __builtin_amdgcn_mfma_f32_16x16x32_bf16(
              aP[a], bP, accO[a][n], 0, 0, 0);
      }
    }
    // next iteration's K-loop barrier protects lPT from overwrite-before-read
  }

  // ---- epilogue: write partial[split][p][j] ----
  float* po = partial + (size_t)split * NPROPS * NIN;
  #pragma unroll
  for (int a = 0; a < 4; ++a)
    #pragma unroll
    for (int n = 0; n < 2; ++n) {
      const int jl = wid * 32 + n * 16 + l15;
      #pragma unroll
      for (int r = 0; r < 4; ++r) {
        const int p = a * 16 + l4 * 4 + r;
        po[(size_t)p * NIN + j0 + jl] = accO[a][n][r];
      }
    }
}

extern "C" void kernel_launch(void* const* d_in, const int* in_sizes, int n_in,
                              void* d_out, int out_size, void* d_ws, size_t ws_size,
                              hipStream_t stream) {
  (void)in_sizes; (void)n_in; (void)out_size;
  const float* Alpha = (const float*)d_in[0];
  const float* X_ref = (const float*)d_in[1];
  const float* desc  = (const float*)d_in[2];
  const int*   Z_ref = (const int*)d_in[3];
  const int*   Z     = (const int*)d_in[4];
  const int*   expK  = (const int*)d_in[5];
  float* out = (float*)d_out;

  char* ws = (char*)d_ws;
  size_t off = 0;
  auto alloc = [&](size_t b) { void* p = ws + off; off = (off + b + 255) & ~255ULL; return p; };

  __hip_bfloat16* Xr_bf = (__hip_bfloat16*)alloc((size_t)NREF * DFEAT * 2);
  __hip_bfloat16* Xi_bf = (__hip_bfloat16*)alloc((size_t)NIN * DFEAT * 2);
  __hip_bfloat16* Ab    = (__hip_bfloat16*)alloc((size_t)NPROPS * NREF * 2);

  int nsplit = 8;   // 64 j-blocks * 8 splits = 512 blocks = 2/CU
  while (nsplit > 1 && off + (size_t)nsplit * NPROPS * NIN * 4 > ws_size) nsplit >>= 1;
  float* partial = (float*)alloc((size_t)nsplit * NPROPS * NIN * 4);

  { int n4 = NREF * DFEAT / 4;
    cvt_f32_bf16<<<dim3((n4 + 255) / 256), 256, 0, stream>>>(X_ref, Xr_bf, n4); }
  { int n4 = NIN * DFEAT / 4;
    cvt_f32_bf16<<<dim3((n4 + 255) / 256), 256, 0, stream>>>(desc, Xi_bf, n4); }
  { int n4 = NPROPS * NREF / 4;
    cvt_f32_bf16<<<dim3((n4 + 255) / 256), 256, 0, stream>>>(Alpha, Ab, n4); }

  const int i_per_split = NREF / nsplit;
  fused_poly_kernel<<<dim3(NIN / BJ, nsplit), 256, 0, stream>>>(
      Xr_bf, Xi_bf, Ab, Z_ref, Z, expK, partial, i_per_split);

  reduce_partials<<<dim3(NPROPS * NIN / 4 / 256), 256, 0, stream>>>(partial, out, nsplit);
}